// Round 14
// baseline (182.912 us; speedup 1.0000x reference)
//
#include <hip/hip_runtime.h>

constexpr int Sc = 4096, Dc = 64;
constexpr int BH = 128;
constexpr int SROWS = 32;                 // s-rows per stage (one MFMA K-step)
constexpr int MM = Dc * Dc;               // 4096 floats of M per (bh)
constexpr int QT = 128;                   // q-rows per block in k3

using sh8 = __attribute__((ext_vector_type(8))) short;
using f32x4 = __attribute__((ext_vector_type(4))) float;

__device__ __forceinline__ unsigned int packbf2(float lo, float hi) {
  // two RNE float->bf16 packed into one dword (bit-identical to R9/R11/R13 pass)
  unsigned int a = __builtin_bit_cast(unsigned int, lo);
  unsigned int b = __builtin_bit_cast(unsigned int, hi);
  a = (a + 0x7fffu + ((a >> 16) & 1u)) >> 16;
  b = (b + 0x7fffu + ((b >> 16) & 1u)) & 0xffff0000u;
  return a | b;
}

// ---- Kernel 1: M = K^T V via bf16 MFMA, direct-global fragment gather ----
// R11 body verbatim (VGPR=56 -> 8 waves/SIMD bucket), SS templated: SS=16 gives
// grid 2048 -> 8 blocks/CU -> 32 waves/CU. Waves are fully independent (no LDS,
// no barriers), so occupancy converts directly into latency coverage.
template<int SSL>
__global__ __launch_bounds__(256) void k1_accum(const float* __restrict__ K,
                                                const float* __restrict__ V,
                                                float* __restrict__ Pm,
                                                double* __restrict__ Pz) {
  constexpr int CH = Sc / SSL;
  constexpr int NS = CH / SROWS;
  const int blk = blockIdx.x, bh = blk / SSL, ck = blk % SSL;
  const int tid = threadIdx.x, w = tid >> 6, l = tid & 63;
  const int g = l >> 4, c = l & 15;

  const size_t base = ((size_t)bh * Sc + (size_t)ck * CH) * Dc;
  // lane-fixed columns: A reads K[.][16w+c]; B reads V[.][16et+c]
  const float* kcol = K + base + 16 * w + c;
  const float* vcol = V + base + c;

  f32x4 acc[4];
  #pragma unroll
  for (int i = 0; i < 4; ++i) acc[i] = (f32x4){0.f, 0.f, 0.f, 0.f};
  double zacc = 0.0;

  for (int st = 0; st < NS; ++st) {
    const int rowf = (st * SROWS + 8 * g) * Dc;   // float offset of lane's 8-row slab

    float ak[8];
    #pragma unroll
    for (int j = 0; j < 8; ++j) ak[j] = kcol[rowf + j * Dc];

    float bv[4][8];
    #pragma unroll
    for (int et = 0; et < 4; ++et)
      #pragma unroll
      for (int j = 0; j < 8; ++j) bv[et][j] = vcol[rowf + j * Dc + 16 * et];

    // z partial: lane owns d = 16w+c, rows 8g..8g+8 of this stage (f64, order-free)
    #pragma unroll
    for (int j = 0; j < 8; ++j) zacc += (double)ak[j];

    // pack to bf16 fragments (RNE, identical to staged path)
    unsigned int au[4];
    #pragma unroll
    for (int j = 0; j < 4; ++j) au[j] = packbf2(ak[2 * j], ak[2 * j + 1]);
    const sh8 afr = __builtin_bit_cast(sh8, *(const uint4*)au);

    #pragma unroll
    for (int et = 0; et < 4; ++et) {
      unsigned int bu[4];
      #pragma unroll
      for (int j = 0; j < 4; ++j) bu[j] = packbf2(bv[et][2 * j], bv[et][2 * j + 1]);
      const sh8 bfr = __builtin_bit_cast(sh8, *(const uint4*)bu);
      acc[et] = __builtin_amdgcn_mfma_f32_16x16x32_bf16(afr, bfr, acc[et], 0, 0, 0);
    }
  }

  // Pm partial: D layout col=lane&15 -> e=16et+c, row=(lane>>4)*4+r -> d=16w+4g+r
  float* pd = Pm + ((size_t)ck * BH + bh) * MM;
  #pragma unroll
  for (int et = 0; et < 4; ++et)
    #pragma unroll
    for (int r = 0; r < 4; ++r)
      pd[(16 * w + 4 * g + r) * 64 + 16 * et + c] = acc[et][r];

  // z partial p = ck*4 + g, component d = 16w + c  (each (p,d) written once)
  Pz[((size_t)(ck * 4 + g) * BH + bh) * Dc + 16 * w + c] = zacc;
}

// ---- Kernel 2: reduce M partials (f32); z = f64 exact sum ROUNDED TO F32 ----
__global__ __launch_bounds__(256) void k2_reduce(const float* __restrict__ Pm,
                                                 const double* __restrict__ Pz,
                                                 float* __restrict__ Fm,
                                                 float* __restrict__ Fz,
                                                 int ss, int nzp) {
  const int i = blockIdx.x * 256 + threadIdx.x;
  const int nm = BH * MM;
  if (i < nm) {
    float s = 0.f;
    for (int cc = 0; cc < ss; ++cc) s += Pm[(size_t)cc * nm + i];
    Fm[i] = s;
  }
  const int nz = BH * Dc;
  if (i < nz) {
    double s = 0.0;
    for (int cc = 0; cc < nzp; ++cc) s += Pz[(size_t)cc * nz + i];
    Fz[i] = (float)s;   // f32 intermediate matches np bitwise
  }
}

// ---- Kernel 3: out = (q @ M) / (q . z_f32 + eps); 4 rows x 8 cols per thread ----
__global__ __launch_bounds__(256) void k3_retrieve(const float* __restrict__ Q,
                                                   const float* __restrict__ Fm,
                                                   const float* __restrict__ Fz,
                                                   float* __restrict__ O) {
  const int blk = blockIdx.x;             // BH * (Sc/QT) = 128*32
  const int bh = blk >> 5;
  const int row0 = (blk & 31) * QT;

  __shared__ __align__(16) float lm[Dc][Dc];     // 16 KB
  __shared__ __align__(16) float lq[QT][68];     // padded: row stride 68 floats
  __shared__ __align__(16) float lz[Dc];         // f32 z (the np intermediate)

  const int tid = threadIdx.x;

  // stage M: contiguous 16 KB
  const float4* gm4 = (const float4*)(Fm + (size_t)bh * MM);
  float4* lm4 = (float4*)&lm[0][0];
  #pragma unroll
  for (int j = 0; j < 4; ++j) lm4[tid + j * 256] = gm4[tid + j * 256];
  if (tid < Dc) lz[tid] = Fz[(size_t)bh * Dc + tid];

  // stage q rows (coalesced global, padded LDS rows)
  const float4* gq4 = (const float4*)(Q + ((size_t)bh * Sc + row0) * Dc);
  #pragma unroll
  for (int j = 0; j < 8; ++j) {
    const int i4 = tid + j * 256;
    const float4 v = gq4[i4];
    const int f = i4 * 4;
    *(float4*)&lq[f >> 6][f & 63] = v;
  }
  __syncthreads();

  const int rg = tid >> 3;       // 0..31 -> row quad
  const int cg = tid & 7;        // 0..7  -> 8-col block
  const int r0 = rg * 4;
  const int e0 = cg * 8;

  float acc[4][8] = {};
  double den[4] = {0.0, 0.0, 0.0, 0.0};

  #pragma unroll
  for (int ds = 0; ds < 16; ++ds) {
    const int d0 = ds * 4;
    const float4 z4 = *(const float4*)&lz[d0];
    const float* zf = (const float*)&z4;
    float4 q4[4];
    #pragma unroll
    for (int r = 0; r < 4; ++r) q4[r] = *(const float4*)&lq[r0 + r][d0];
    const float* qf[4] = {(const float*)&q4[0], (const float*)&q4[1],
                          (const float*)&q4[2], (const float*)&q4[3]};
    #pragma unroll
    for (int i = 0; i < 4; ++i) {
      const float4 ma = *(const float4*)&lm[d0 + i][e0];
      const float4 mb = *(const float4*)&lm[d0 + i][e0 + 4];
      const float mf[8] = {ma.x, ma.y, ma.z, ma.w, mb.x, mb.y, mb.z, mb.w};
      const double zd = (double)zf[i];
      #pragma unroll
      for (int r = 0; r < 4; ++r) {
        const float qs = qf[r][i];
        den[r] += (double)qs * zd;
        #pragma unroll
        for (int j = 0; j < 8; ++j)
          acc[r][j] = fmaf(qs, mf[j], acc[r][j]);
      }
    }
  }

  #pragma unroll
  for (int r = 0; r < 4; ++r) {
    const double iv = 1.0 / (den[r] + 1e-6);
    float* go = O + ((size_t)bh * Sc + row0 + r0 + r) * Dc + e0;
    ((float4*)go)[0] = make_float4((float)((double)acc[r][0] * iv),
                                   (float)((double)acc[r][1] * iv),
                                   (float)((double)acc[r][2] * iv),
                                   (float)((double)acc[r][3] * iv));
    ((float4*)go)[1] = make_float4((float)((double)acc[r][4] * iv),
                                   (float)((double)acc[r][5] * iv),
                                   (float)((double)acc[r][6] * iv),
                                   (float)((double)acc[r][7] * iv));
  }
}

extern "C" void kernel_launch(void* const* d_in, const int* in_sizes, int n_in,
                              void* d_out, int out_size, void* d_ws, size_t ws_size,
                              hipStream_t stream) {
  const float* K = (const float*)d_in[0];   // keys    [B,H,S,D]
  const float* V = (const float*)d_in[1];   // values
  const float* Q = (const float*)d_in[2];   // queries
  float* O = (float*)d_out;                 // [B,H,S,D]

  // SS=16 needs: Pm 33.55MB + Fm 2.10MB + Pz(64 partials) 4.19MB + Fz 0.03MB ~= 39.9MB
  const size_t need16 = (size_t)16 * BH * MM * 4 + (size_t)BH * MM * 4 +
                        (size_t)64 * BH * Dc * 8 + (size_t)BH * Dc * 4;
  const int ss = (ws_size >= need16) ? 16 : 8;
  const int nzp = ss * 4;

  float* Pm = (float*)d_ws;                                  // ss*BH*MM floats
  float* Fm = Pm + (size_t)ss * BH * MM;                     // BH*MM floats
  double* Pz = (double*)(Fm + (size_t)BH * MM);              // nzp*BH*Dc doubles
  float* Fz = (float*)(Pz + (size_t)nzp * BH * Dc);          // BH*Dc floats

  if (ss == 16)
    hipLaunchKernelGGL(k1_accum<16>, dim3(BH * 16), dim3(256), 0, stream, K, V, Pm, Pz);
  else
    hipLaunchKernelGGL(k1_accum<8>, dim3(BH * 8), dim3(256), 0, stream, K, V, Pm, Pz);
  hipLaunchKernelGGL(k2_reduce, dim3((BH * MM + 255) / 256), dim3(256), 0, stream,
                     Pm, Pz, Fm, Fz, ss, nzp);
  hipLaunchKernelGGL(k3_retrieve, dim3(BH * (Sc / QT)), dim3(256), 0, stream, Q, Fm, Fz, O);
}

// Round 15
// 162.780 us; speedup vs baseline: 1.1237x; 1.1237x over previous
//
#include <hip/hip_runtime.h>

constexpr int Sc = 4096, Dc = 64;
constexpr int BH = 128;
constexpr int SS = 8;                     // s-split chunks in k1
constexpr int CHUNK = Sc / SS;            // 512 rows per block
constexpr int SROWS = 32;                 // s-rows per stage (one MFMA K-step)
constexpr int NST = CHUNK / SROWS;        // 16 stages
constexpr int MM = Dc * Dc;               // 4096 floats of M per (bh)
constexpr int NZP = SS * 4;               // 32 z partials
constexpr int QT = 128;                   // q-rows per block in k3

using sh8 = __attribute__((ext_vector_type(8))) short;
using f32x4 = __attribute__((ext_vector_type(4))) float;
typedef __attribute__((address_space(1))) const unsigned int as1_u32;
typedef __attribute__((address_space(3))) unsigned int as3_u32;

__device__ __forceinline__ unsigned int packbf2(float lo, float hi) {
  // two RNE float->bf16 packed into one dword (bit-identical to R9..R14 pass)
  unsigned int a = __builtin_bit_cast(unsigned int, lo);
  unsigned int b = __builtin_bit_cast(unsigned int, hi);
  a = (a + 0x7fffu + ((a >> 16) & 1u)) >> 16;
  b = (b + 0x7fffu + ((b >> 16) & 1u)) & 0xffff0000u;
  return a | b;
}

// ---- Kernel 1: M = K^T V via bf16 MFMA; global_load_lds staging, 2-phase ----
// T3 minimum 2-phase: STAGE(t+1) after raw barrier, compute t, counted waits.
// Loads for t+1 have the full stage-t compute phase (~1900 cyc across 4 waves/SIMD)
// to cover HBM latency; no compiler vmcnt(0)-per-chunk serialization (the ~110us
// plateau of R5..R14 was per-wave MLP ~2-3 from register-gather chunking).
__global__ __launch_bounds__(256) void k1_accum(const float* __restrict__ K,
                                                const float* __restrict__ V,
                                                float* __restrict__ Pm,
                                                double* __restrict__ Pz) {
  const int blk = blockIdx.x, bh = blk >> 3, ck = blk & 7;
  const int tid = threadIdx.x, w = tid >> 6, l = tid & 63;
  const int g = l >> 4, c = l & 15;

  const size_t base = ((size_t)bh * Sc + (size_t)ck * CHUNK) * Dc;
  const float* Kg = K + base;
  const float* Vg = V + base;

  // buf b: K tile at [b*4096 .. +2048), V tile at [b*4096+2048 .. +2048)  (32 KB)
  __shared__ __align__(16) float smem[2 * 4096];

  const int lofs = w * 512 + l * 4;     // per-lane float offset within a stage array

  f32x4 acc[4];
  #pragma unroll
  for (int i = 0; i < 4; ++i) acc[i] = (f32x4){0.f, 0.f, 0.f, 0.f};
  double zacc = 0.0;

#define K1_ISSUE(T, BUF)                                                         \
  {                                                                              \
    const float* gk_ = Kg + (size_t)(T) * 2048 + lofs;                           \
    const float* gv_ = Vg + (size_t)(T) * 2048 + lofs;                           \
    float* lk_ = &smem[(BUF) * 4096 + w * 512];        /* wave-uniform base */   \
    float* lv_ = &smem[(BUF) * 4096 + 2048 + w * 512];                           \
    __builtin_amdgcn_global_load_lds((as1_u32*)gk_,         (as3_u32*)lk_,         16, 0, 0); \
    __builtin_amdgcn_global_load_lds((as1_u32*)(gk_ + 256), (as3_u32*)(lk_ + 256), 16, 0, 0); \
    __builtin_amdgcn_global_load_lds((as1_u32*)gv_,         (as3_u32*)lv_,         16, 0, 0); \
    __builtin_amdgcn_global_load_lds((as1_u32*)(gv_ + 256), (as3_u32*)(lv_ + 256), 16, 0, 0); \
  }

  K1_ISSUE(0, 0)

  for (int t = 0; t < NST; ++t) {
    const int buf = t & 1;
    asm volatile("s_waitcnt vmcnt(0)" ::: "memory");   // stage t landed (this wave)
    asm volatile("s_waitcnt lgkmcnt(0)" ::: "memory"); // prior ds ops drained
    __builtin_amdgcn_s_barrier();                      // all waves: t resident, t-1 reads done
    if (t + 1 < NST) K1_ISSUE(t + 1, buf ^ 1)          // overwrite t-1's buffer (safe)

    const float* bK = &smem[buf * 4096];
    const float* bV = &smem[buf * 4096 + 2048];

    // z: wave w sums rows 8w..8w+8, lane l owns col l (f64, order-free)
    #pragma unroll
    for (int r = 0; r < 8; ++r) zacc += (double)bK[(8 * w + r) * 64 + l];

    // A fragment: lane (g,c) reads K[8g+j][16w+c]
    float ak[8];
    #pragma unroll
    for (int j = 0; j < 8; ++j) ak[j] = bK[(8 * g + j) * 64 + 16 * w + c];
    unsigned int au[4];
    #pragma unroll
    for (int j = 0; j < 4; ++j) au[j] = packbf2(ak[2 * j], ak[2 * j + 1]);
    const sh8 afr = __builtin_bit_cast(sh8, *(const uint4*)au);

    #pragma unroll
    for (int et = 0; et < 4; ++et) {
      float bv[8];
      #pragma unroll
      for (int j = 0; j < 8; ++j) bv[j] = bV[(8 * g + j) * 64 + 16 * et + c];
      unsigned int bu[4];
      #pragma unroll
      for (int j = 0; j < 4; ++j) bu[j] = packbf2(bv[2 * j], bv[2 * j + 1]);
      const sh8 bfr = __builtin_bit_cast(sh8, *(const uint4*)bu);
      acc[et] = __builtin_amdgcn_mfma_f32_16x16x32_bf16(afr, bfr, acc[et], 0, 0, 0);
    }
  }
#undef K1_ISSUE

  // Pm partial: D layout col=lane&15 -> e=16et+c, row=(lane>>4)*4+r -> d=16w+4g+r
  float* pd = Pm + ((size_t)ck * BH + bh) * MM;
  #pragma unroll
  for (int et = 0; et < 4; ++et)
    #pragma unroll
    for (int r = 0; r < 4; ++r)
      pd[(16 * w + 4 * g + r) * 64 + 16 * et + c] = acc[et][r];

  // z partial p = ck*4 + w, component d = l (each (p,d) written once)
  Pz[((size_t)(ck * 4 + w) * BH + bh) * Dc + l] = zacc;
}

// ---- Kernel 2: reduce M partials (f32); z = f64 exact sum ROUNDED TO F32 ----
__global__ __launch_bounds__(256) void k2_reduce(const float* __restrict__ Pm,
                                                 const double* __restrict__ Pz,
                                                 float* __restrict__ Fm,
                                                 float* __restrict__ Fz) {
  const int i = blockIdx.x * 256 + threadIdx.x;
  const int nm = BH * MM;
  if (i < nm) {
    float s = 0.f;
    #pragma unroll
    for (int cc = 0; cc < SS; ++cc) s += Pm[(size_t)cc * nm + i];
    Fm[i] = s;
  }
  const int nz = BH * Dc;
  if (i < nz) {
    double s = 0.0;
    #pragma unroll
    for (int cc = 0; cc < NZP; ++cc) s += Pz[(size_t)cc * nz + i];
    Fz[i] = (float)s;   // f32 intermediate matches np bitwise
  }
}

// ---- Kernel 3: out = (q @ M) / (q . z_f32 + eps); 4 rows x 8 cols per thread ----
__global__ __launch_bounds__(256) void k3_retrieve(const float* __restrict__ Q,
                                                   const float* __restrict__ Fm,
                                                   const float* __restrict__ Fz,
                                                   float* __restrict__ O) {
  const int blk = blockIdx.x;             // BH * (Sc/QT) = 128*32
  const int bh = blk >> 5;
  const int row0 = (blk & 31) * QT;

  __shared__ __align__(16) float lm[Dc][Dc];     // 16 KB
  __shared__ __align__(16) float lq[QT][68];     // padded: row stride 68 floats
  __shared__ __align__(16) float lz[Dc];         // f32 z (the np intermediate)

  const int tid = threadIdx.x;

  // stage M: contiguous 16 KB
  const float4* gm4 = (const float4*)(Fm + (size_t)bh * MM);
  float4* lm4 = (float4*)&lm[0][0];
  #pragma unroll
  for (int j = 0; j < 4; ++j) lm4[tid + j * 256] = gm4[tid + j * 256];
  if (tid < Dc) lz[tid] = Fz[(size_t)bh * Dc + tid];

  // stage q rows (coalesced global, padded LDS rows)
  const float4* gq4 = (const float4*)(Q + ((size_t)bh * Sc + row0) * Dc);
  #pragma unroll
  for (int j = 0; j < 8; ++j) {
    const int i4 = tid + j * 256;
    const float4 v = gq4[i4];
    const int f = i4 * 4;
    *(float4*)&lq[f >> 6][f & 63] = v;
  }
  __syncthreads();

  const int rg = tid >> 3;       // 0..31 -> row quad
  const int cg = tid & 7;        // 0..7  -> 8-col block
  const int r0 = rg * 4;
  const int e0 = cg * 8;

  float acc[4][8] = {};
  double den[4] = {0.0, 0.0, 0.0, 0.0};

  #pragma unroll
  for (int ds = 0; ds < 16; ++ds) {
    const int d0 = ds * 4;
    const float4 z4 = *(const float4*)&lz[d0];
    const float* zf = (const float*)&z4;
    float4 q4[4];
    #pragma unroll
    for (int r = 0; r < 4; ++r) q4[r] = *(const float4*)&lq[r0 + r][d0];
    const float* qf[4] = {(const float*)&q4[0], (const float*)&q4[1],
                          (const float*)&q4[2], (const float*)&q4[3]};
    #pragma unroll
    for (int i = 0; i < 4; ++i) {
      const float4 ma = *(const float4*)&lm[d0 + i][e0];
      const float4 mb = *(const float4*)&lm[d0 + i][e0 + 4];
      const float mf[8] = {ma.x, ma.y, ma.z, ma.w, mb.x, mb.y, mb.z, mb.w};
      const double zd = (double)zf[i];
      #pragma unroll
      for (int r = 0; r < 4; ++r) {
        const float qs = qf[r][i];
        den[r] += (double)qs * zd;
        #pragma unroll
        for (int j = 0; j < 8; ++j)
          acc[r][j] = fmaf(qs, mf[j], acc[r][j]);
      }
    }
  }

  #pragma unroll
  for (int r = 0; r < 4; ++r) {
    const double iv = 1.0 / (den[r] + 1e-6);
    float* go = O + ((size_t)bh * Sc + row0 + r0 + r) * Dc + e0;
    ((float4*)go)[0] = make_float4((float)((double)acc[r][0] * iv),
                                   (float)((double)acc[r][1] * iv),
                                   (float)((double)acc[r][2] * iv),
                                   (float)((double)acc[r][3] * iv));
    ((float4*)go)[1] = make_float4((float)((double)acc[r][4] * iv),
                                   (float)((double)acc[r][5] * iv),
                                   (float)((double)acc[r][6] * iv),
                                   (float)((double)acc[r][7] * iv));
  }
}

extern "C" void kernel_launch(void* const* d_in, const int* in_sizes, int n_in,
                              void* d_out, int out_size, void* d_ws, size_t ws_size,
                              hipStream_t stream) {
  const float* K = (const float*)d_in[0];   // keys    [B,H,S,D]
  const float* V = (const float*)d_in[1];   // values
  const float* Q = (const float*)d_in[2];   // queries
  float* O = (float*)d_out;                 // [B,H,S,D]

  float* Pm = (float*)d_ws;                                  // SS*BH*MM floats   (16.8 MB)
  float* Fm = Pm + (size_t)SS * BH * MM;                     // BH*MM floats      (2.1 MB)
  double* Pz = (double*)(Fm + (size_t)BH * MM);              // NZP*BH*Dc doubles (2.1 MB)
  float* Fz = (float*)(Pz + (size_t)NZP * BH * Dc);          // BH*Dc floats      (32 KB)

  hipLaunchKernelGGL(k1_accum, dim3(BH * SS), dim3(256), 0, stream, K, V, Pm, Pz);
  hipLaunchKernelGGL(k2_reduce, dim3((BH * MM + 255) / 256), dim3(256), 0, stream, Pm, Pz, Fm, Fz);
  hipLaunchKernelGGL(k3_retrieve, dim3(BH * (Sc / QT)), dim3(256), 0, stream, Q, Fm, Fz, O);
}